// Round 4
// baseline (58.553 us; speedup 1.0000x reference)
//
#include <hip/hip_runtime.h>
#include <stdint.h>

// AeTransformer_44839458570443: 3-NN inverse-distance interpolation + (tanh+1)/2.
// xyz1: [B,3,N] fp32, xyz2: [B,3,S] fp32, points2: [B,1,S] fp32 -> out [B,N] fp32.
//
// Selection bit-matches the reference's float32 expanded distance
//   d = (-2*((x*x'+y*y')+z*z') + ||q||^2) + ||p||^2    (fp32, no FMA)
// ordered by (d, index). SCREEN: per-wave FMA proxy keys (quantized d | idx),
// candidates split 2 ways across wave pairs, each keeping a sorted 5-slot
// min-list (v_med3). REFINE: 10 survivors re-scored with the exact replicated
// fp32 sequence and sorted by (d, idx)  (proven in rounds 2-3).
static constexpr int B = 4;
static constexpr int N = 65536;
static constexpr int S = 512;

// Pack per-sample constants: (x, y, z, ((x*x + y*y) + z*z)) with IEEE fp32 ops
__global__ __launch_bounds__(256) void prep_kernel(const float* __restrict__ xyz2,
                                                   float4* __restrict__ ws) {
    int t = blockIdx.x * 256 + threadIdx.x;
    if (t >= B * S) return;
    int b = t / S, s = t - b * S;
    const float* p = xyz2 + (size_t)b * 3 * S;
    float x = p[s], y = p[s + S], z = p[s + 2 * S];
    float c = __fadd_rn(__fadd_rn(__fmul_rn(x, x), __fmul_rn(y, y)), __fmul_rn(z, z));
    ws[t] = make_float4(x, y, z, c);
}

// Reference-replicated fp32 distance (numpy order, no contraction)
__device__ __forceinline__ float ref_d(float x1, float y1, float z1, float ssrc, float4 p) {
    float dot = __fadd_rn(__fadd_rn(__fmul_rn(x1, p.x), __fmul_rn(y1, p.y)),
                          __fmul_rn(z1, p.z));
    float t = __fmul_rn(dot, -2.0f);
    return __fadd_rn(__fadd_rn(t, ssrc), p.w);
}

// compare-and-swap on (d, idx) ascending, idx ascending on exact float ties
#define CAS(da_, ia_, db_, ib_)                                     \
    {                                                               \
        bool sw_ = (db_ < da_) || ((db_ == da_) && (ib_ < ia_));    \
        float tda_ = sw_ ? db_ : da_;                               \
        int tia_ = sw_ ? ib_ : ia_;                                 \
        db_ = sw_ ? da_ : db_;                                      \
        ib_ = sw_ ? ia_ : ib_;                                      \
        da_ = tda_;                                                 \
        ia_ = tia_;                                                 \
    }

__global__ __launch_bounds__(256, 8) void knn3_kernel(const float* __restrict__ xyz1,
                                                      const float* __restrict__ points2,
                                                      const float4* __restrict__ ws,
                                                      float* __restrict__ out) {
    __shared__ uint32_t keys_sh[256][5];  // 5 KB survivor exchange
    const int tid = threadIdx.x;
    const int lane = tid & 63;
    const int wid = tid >> 6;            // 4 waves: pairs (0,1) and (2,3)
    const int half = wid & 1;            // which 256-candidate half this wave scans
    const int qg = wid >> 1;             // which 64-query group

    // block-uniform batch; per-lane query index
    const int b = blockIdx.x >> 9;                       // 512 blocks per batch
    const int n = ((blockIdx.x & 511) << 7) + (qg << 6) + lane;

    const float* q = xyz1 + (size_t)b * 3 * N;
    float x1 = q[n], y1 = q[n + N], z1 = q[n + 2 * N];
    float ssrc = __fadd_rn(__fadd_rn(__fmul_rn(x1, x1), __fmul_rn(y1, y1)),
                           __fmul_rn(z1, z1));
    // screen-only per-query constants (proxy zone; refine is exact)
    float c = ssrc + 0.25f;  // bias keeps key > 0
    float nx2 = -2.0f * x1, ny2 = -2.0f * y1, nz2 = -2.0f * z1;

    // Wave-uniform half index, laundered through readfirstlane so the table
    // address is provably uniform -> scalar s_load path (K$), not LDS/VMEM.
    const int half_u = __builtin_amdgcn_readfirstlane(half);
    const float4* __restrict__ wsrc = ws + b * S + half_u * 256;

    // 5 smallest packed keys ascending; key = float(proxy d + 0.25) with low
    // 8 mantissa bits = local candidate index (monotone bucket, idx tiebreak).
    float m0 = 3.0e38f, m1 = 3.0e38f, m2 = 3.0e38f, m3 = 3.0e38f, m4 = 3.0e38f;
#pragma unroll 8
    for (int s = 0; s < 256; ++s) {
        float4 p = wsrc[s];  // uniform address -> s_load_dwordx16 groups
        float t = fmaf(nz2, p.z, c);
        t = fmaf(ny2, p.y, t);
        t = fmaf(nx2, p.x, t);
        float e = t + p.w;
        float k = __uint_as_float((__float_as_uint(e) & 0xFFFFFF00u) | (uint32_t)s);
        // branchless sorted insert: 1 min + 4 med3
        float t4 = __builtin_amdgcn_fmed3f(m3, k, m4);
        float t3 = __builtin_amdgcn_fmed3f(m2, k, m3);
        float t2 = __builtin_amdgcn_fmed3f(m1, k, m2);
        float t1 = __builtin_amdgcn_fmed3f(m0, k, m1);
        m0 = fminf(m0, k);
        m1 = t1; m2 = t2; m3 = t3; m4 = t4;
    }

    keys_sh[tid][0] = __float_as_uint(m0);
    keys_sh[tid][1] = __float_as_uint(m1);
    keys_sh[tid][2] = __float_as_uint(m2);
    keys_sh[tid][3] = __float_as_uint(m3);
    keys_sh[tid][4] = __float_as_uint(m4);
    __syncthreads();
    if (half) return;  // waves 1,3 done; no further barriers

    // Gather 10 survivors: own 5 (global idx = local) + partner 5 (+256)
    int gi[10];
    float dd[10];
    const float4* __restrict__ wall = ws + b * S;
#pragma unroll
    for (int j = 0; j < 5; ++j) {
        gi[j] = (int)(keys_sh[tid][j] & 255u);
        gi[j + 5] = (int)(keys_sh[tid ^ 64][j] & 255u) + 256;
    }
#pragma unroll
    for (int j = 0; j < 10; ++j) dd[j] = ref_d(x1, y1, z1, ssrc, wall[gi[j]]);

    // selection network: bubble smallest 3 to front by (d, idx)
#pragma unroll
    for (int p = 0; p < 3; ++p)
#pragma unroll
        for (int i = 8; i >= p; --i) CAS(dd[i], gi[i], dd[i + 1], gi[i + 1]);

    // Replicate reference weight/interp chain in fp32, nearest-first order
    const float EPS32 = 1e-8f;
    float r0 = __fdiv_rn(1.0f, __fadd_rn(dd[0], EPS32));
    float r1 = __fdiv_rn(1.0f, __fadd_rn(dd[1], EPS32));
    float r2 = __fdiv_rn(1.0f, __fadd_rn(dd[2], EPS32));
    float rs = __fadd_rn(__fadd_rn(r0, r1), r2);
    float w0 = __fdiv_rn(r0, rs);
    float w1 = __fdiv_rn(r1, rs);
    float w2 = __fdiv_rn(r2, rs);
    const float* f = points2 + (size_t)b * S;  // D = 1
    float interp = __fadd_rn(__fadd_rn(__fmul_rn(f[gi[0]], w0), __fmul_rn(f[gi[1]], w1)),
                             __fmul_rn(f[gi[2]], w2));
    float t = tanhf(interp);
    out[((size_t)b << 16) | (uint32_t)n] = __fmul_rn(__fadd_rn(t, 1.0f), 0.5f);
}

extern "C" void kernel_launch(void* const* d_in, const int* in_sizes, int n_in,
                              void* d_out, int out_size, void* d_ws, size_t ws_size,
                              hipStream_t stream) {
    const float* xyz1 = (const float*)d_in[0];
    const float* xyz2 = (const float*)d_in[1];
    const float* points2 = (const float*)d_in[2];
    float* out = (float*)d_out;
    float4* ws = (float4*)d_ws;  // B*S*16 = 32 KB

    prep_kernel<<<(B * S + 255) / 256, 256, 0, stream>>>(xyz2, ws);
    // 2048 blocks: each covers 128 queries (2 wave-pairs x 64)
    knn3_kernel<<<(B * N) / 128, 256, 0, stream>>>(xyz1, points2, ws, out);
}